// Round 16
// baseline (1256.977 us; speedup 1.0000x reference)
//
#include <hip/hip_runtime.h>
#include <hip/hip_bf16.h>

#define B_ 64
#define S_ 2048
#define T_ 256

typedef _Float16 half2_t __attribute__((ext_vector_type(2)));
typedef _Float16 f16x8 __attribute__((ext_vector_type(8)));
typedef __attribute__((ext_vector_type(4))) float f32x4;
typedef __attribute__((ext_vector_type(4))) unsigned u32x4;

__device__ __forceinline__ float fdot2f(half2_t a, half2_t b, float c) {
  return __builtin_amdgcn_fdot2(a, b, c, false);
}
__device__ __forceinline__ half2_t pack2(float a, float b) {
  return __builtin_bit_cast(half2_t, __builtin_amdgcn_cvt_pkrtz(a, b));
}
template <int CTRL>
__device__ __forceinline__ float dpp_max(float v) {
  const int t = __builtin_amdgcn_update_dpp(0, __builtin_bit_cast(int, v), CTRL, 0xF, 0xF, true);
  return fmaxf(v, __builtin_bit_cast(float, t));
}
template <int CTRL>
__device__ __forceinline__ float dpp_add(float v) {
  const int t = __builtin_amdgcn_update_dpp(0, __builtin_bit_cast(int, v), CTRL, 0xF, 0xF, true);
  return v + __builtin_bit_cast(float, t);
}

__device__ __forceinline__ f32x4 mfma16h(f16x8 a, f16x8 b, f32x4 c) {
  return __builtin_amdgcn_mfma_f32_16x16x32_f16(a, b, c, 0, 0, 0);
}

// lgkm-only barrier: LDS visibility; in-flight global register-prefetch untouched
__device__ __forceinline__ void wg_barrier() {
  __builtin_amdgcn_sched_barrier(0);
  asm volatile("s_waitcnt lgkmcnt(0)" ::: "memory");
  __builtin_amdgcn_s_barrier();
  asm volatile("" ::: "memory");
  __builtin_amdgcn_sched_barrier(0);
}

// ---------------- numerator score: ws[b] ----------------
__global__ void crf_score(const float* __restrict__ em, const int* __restrict__ tags,
                          const int* __restrict__ mask, const float* __restrict__ trans,
                          const float* __restrict__ startt, const float* __restrict__ endt,
                          float* __restrict__ ws) {
  const int b = blockIdx.x;
  const int t = threadIdx.x;  // 256
  const int* tg = tags + b * S_;
  const int* mk = mask + b * S_;
  const float* eb = em + (size_t)b * S_ * T_;

  float sc = 0.f;
  int msum = 0;
  for (int s = t; s < S_; s += 256) {
    const int tag = tg[s];
    const int m = mk[s];
    msum += m;
    const float e = eb[(size_t)s * T_ + tag];
    if (s == 0) {
      sc += startt[tag] + e;
    } else {
      const int pt = tg[s - 1];
      sc += (trans[tag * T_ + pt] + e) * (float)m;
    }
  }
#pragma unroll
  for (int off = 32; off > 0; off >>= 1) {
    sc += __shfl_down(sc, off);
    msum += __shfl_down(msum, off);
  }
  __shared__ float ssc[4];
  __shared__ int smc[4];
  const int wv = t >> 6, ln = t & 63;
  if (ln == 0) { ssc[wv] = sc; smc[wv] = msum; }
  __syncthreads();
  if (t == 0) {
    const float s4 = (ssc[0] + ssc[1]) + (ssc[2] + ssc[3]);
    const int m4 = smc[0] + smc[1] + smc[2] + smc[3];
    const int last = tg[m4 - 1];
    ws[b] = s4 + endt[last];
  }
}

// ------- forward (log Z): 1 chain/WG, matrix+vector pipe split -------
// 4 waves x 64 j. Per wave: j-tiles 0,1 (32 j) on MFMA f16 (16 instrs, ~310
// pipe-cy); j-tiles 2,3 (32 j) on v_dot2_f32_f16 (64/lane, issues in the MFMA
// shadow; same A-frag b128 reads; W pre-packed 64 half2/lane; hi-group reduce
// via 2 shfl_xor per column). x stored f16 (r8-proven). Renorm: exact 1-stale
// pow2 from post-E stored-x max, rs folded into exp (r15-proven); int k_run.
// Lane's own output stays at jE = 64w+16hi+lo (hi>=2 coincides with dot2 cols).
#define STEP(RB, WB, P, PV1, PV2)                                                 \
  {                                                                               \
    const float4 q = ((const float4*)&mpT[RB][0])[l & 3];                         \
    const unsigned char* xb = &Xl[RB][0];                                         \
    f16x8 av[8];                                                                  \
    _Pragma("unroll") for (int kk = 0; kk < 8; ++kk)                              \
      av[kk] = *(const f16x8*)(xb + raddr[kk]);                                   \
    f32x4 z4 = {0.f, 0.f, 0.f, 0.f};                                              \
    f32x4 aL0 = z4, aH0 = z4, aL1 = z4, aH1 = z4;                                 \
    _Pragma("unroll") for (int kk = 0; kk < 4; ++kk) {                            \
      aL0 = mfma16h(av[kk], wf[0][kk], aL0);                                      \
      aL1 = mfma16h(av[kk], wf[1][kk], aL1);                                      \
    }                                                                             \
    _Pragma("unroll") for (int kk = 4; kk < 8; ++kk) {                            \
      aH0 = mfma16h(av[kk], wf[0][kk], aH0);                                      \
      aH1 = mfma16h(av[kk], wf[1][kk], aH1);                                      \
    }                                                                             \
    float v1a = 0.f, v1b = 0.f, v1c = 0.f, v1d = 0.f;                             \
    float v2a = 0.f, v2b = 0.f, v2c = 0.f, v2d = 0.f;                             \
    _Pragma("unroll") for (int kk = 0; kk < 8; ++kk) {                            \
      const u32x4 u = __builtin_bit_cast(u32x4, av[kk]);                          \
      const half2_t h0 = __builtin_bit_cast(half2_t, u.x);                        \
      const half2_t h1 = __builtin_bit_cast(half2_t, u.y);                        \
      const half2_t h2 = __builtin_bit_cast(half2_t, u.z);                        \
      const half2_t h3 = __builtin_bit_cast(half2_t, u.w);                        \
      v1a = fdot2f(h0, Wd1[kk][0], v1a);                                          \
      v1b = fdot2f(h1, Wd1[kk][1], v1b);                                          \
      v1c = fdot2f(h2, Wd1[kk][2], v1c);                                          \
      v1d = fdot2f(h3, Wd1[kk][3], v1d);                                          \
      v2a = fdot2f(h0, Wd2[kk][0], v2a);                                          \
      v2b = fdot2f(h1, Wd2[kk][1], v2b);                                          \
      v2c = fdot2f(h2, Wd2[kk][2], v2c);                                          \
      v2d = fdot2f(h3, Wd2[kk][3], v2d);                                          \
    }                                                                             \
    float zv1 = (v1a + v1b) + (v1c + v1d);                                        \
    float zv2 = (v2a + v2b) + (v2c + v2d);                                        \
    zv1 += __shfl_xor(zv1, 16); zv1 += __shfl_xor(zv1, 32);                       \
    zv2 += __shfl_xor(zv2, 16); zv2 += __shfl_xor(zv2, 32);                       \
    float mh = fmaxf(fmaxf(q.x, q.y), fmaxf(q.z, q.w));                           \
    mh = dpp_max<0xB1>(mh);                                                       \
    mh = dpp_max<0x4E>(mh);                                                       \
    int ue = (int)(__builtin_bit_cast(unsigned, mh) >> 23) - 127;                 \
    ue = (ue < -20) ? -20 : ue;                                                   \
    ue += 8;                                                                      \
    k_run += ue;                                                                  \
    const float kln = -0.6931471805599453f * (float)ue;                           \
    const float EcRs = __expf(P + kln);                                           \
    const float EcRsV1 = __expf(PV1 + kln);                                       \
    const float EcRsV2 = __expf(PV2 + kln);                                       \
    P = emL[cOff + rowf];                                                         \
    PV1 = emV1[cOff + rowf];                                                      \
    PV2 = emV2[cOff + rowf];                                                      \
    rowf = (rowf < 2047u * 256u) ? rowf + 256u : rowf;                            \
    const f32x4 ac0 = aL0 + aH0, ac1 = aL1 + aH1;                                 \
    const float valm = (hi & 1) ? ac1[0] : ac0[0];                                \
    const float xm = valm * EcRs;                                                 \
    const float xv1 = zv1 * EcRsV1;                                               \
    const float xv2 = zv2 * EcRsV2;                                               \
    const float own = (hi < 2) ? xm : ((hi == 2) ? xv1 : xv2);                    \
    float mx = fmaxf(own, fmaxf(xv1, xv2));                                       \
    mx = dpp_max<0xB1>(mx);                                                       \
    mx = dpp_max<0x4E>(mx);                                                       \
    mx = dpp_max<0x141>(mx);                                                      \
    mx = dpp_max<0x140>(mx);                                                      \
    if (lo == 0) mpT[WB][w * 4 + hi] = mx;                                        \
    *(_Float16*)(&Xl[WB][0] + waddr) = (_Float16)own;                             \
    wg_barrier();                                                                 \
  }

__global__ __launch_bounds__(256, 1) void crf_forward(
    const float* __restrict__ em, const float* __restrict__ trans,
    const float* __restrict__ startt, const float* __restrict__ endt,
    float* __restrict__ ws) {
  const int tid = threadIdx.x;
  const int w = tid >> 6;
  const int l = tid & 63;
  const int lo = l & 15;
  const int hi = l >> 4;

  __shared__ __align__(16) unsigned char Xl[2][512];  // x f16, one 256-wide row
  __shared__ __align__(16) float mpT[2][16];
  __shared__ float fsum[4];

  // ---- W MFMA fragments (tiles 0,1): 64 VGPRs
  f16x8 wf[2][4 + 4];
#pragma unroll
  for (int t = 0; t < 2; ++t) {
    const int j = 64 * w + 16 * t + lo;
#pragma unroll
    for (int kk = 0; kk < 8; ++kk) {
      f16x8 v;
#pragma unroll
      for (int e = 0; e < 8; ++e) {
        const int k = kk * 32 + hi * 8 + e;
        v[e] = (_Float16)__expf(trans[k * T_ + j]);
      }
      wf[t][kk] = v;
    }
  }
  // ---- W dot2 slices (tiles 2,3): j1 = 64w+32+lo, j2 = 64w+48+lo; 64 half2
  half2_t Wd1[8][4], Wd2[8][4];
  {
    const int j1 = 64 * w + 32 + lo;
    const int j2 = 64 * w + 48 + lo;
#pragma unroll
    for (int kk = 0; kk < 8; ++kk)
#pragma unroll
      for (int p = 0; p < 4; ++p) {
        const int k0 = kk * 32 + hi * 8 + 2 * p;
        Wd1[kk][p] = pack2(__expf(trans[k0 * T_ + j1]), __expf(trans[(k0 + 1) * T_ + j1]));
        Wd2[kk][p] = pack2(__expf(trans[k0 * T_ + j2]), __expf(trans[(k0 + 1) * T_ + j2]));
      }
  }

  // ---- addresses
  unsigned raddr[8];
#pragma unroll
  for (int kk = 0; kk < 8; ++kk) raddr[kk] = (unsigned)(16 * ((4 * kk + hi) & 31));
  const int jE = 64 * w + 16 * hi + lo;   // own column (hi>=2: == dot2 cols)
  const unsigned waddr = (unsigned)(16 * ((jE >> 3) & 31) + (jE & 7) * 2);
  const float* emL = em + jE;
  const float* emV1 = em + 64 * w + 32 + lo;
  const float* emV2 = em + 64 * w + 48 + lo;
  const unsigned cOff = (unsigned)(blockIdx.x * (S_ * T_));

  // ---- init: al0 = start + em[.,0,.]; exact max m0
  float m0;
  {
    const float al = startt[jE] + emL[cOff];
    float lm = al;
    lm = dpp_max<0xB1>(lm);
    lm = dpp_max<0x4E>(lm);
    lm = dpp_max<0x141>(lm);
    lm = dpp_max<0x140>(lm);
    lm = fmaxf(lm, __shfl_xor(lm, 16));
    lm = fmaxf(lm, __shfl_xor(lm, 32));
    if (l == 0) fsum[w] = lm;
    __syncthreads();
    m0 = fmaxf(fmaxf(fsum[0], fsum[1]), fmaxf(fsum[2], fsum[3]));
    const float x0 = __expf(al - m0);
    *(_Float16*)(&Xl[0][0] + waddr) = (_Float16)x0;
    if (tid < 16) mpT[0][tid] = 1.0f;  // max(x0) == 1 exactly
  }
  // ---- E register prefetch rings (rows 1 and 2)
  float P0 = emL[cOff + 256], P1 = emL[cOff + 512];
  float PV1a = emV1[cOff + 256], PV1b = emV1[cOff + 512];
  float PV2a = emV2[cOff + 256], PV2b = emV2[cOff + 512];
  unsigned rowf = 3u * 256u;
  int k_run = 0;
  __syncthreads();

  // ---- main loop: steps 1..2046 as pairs, tail 2047
  for (int p2 = 0; p2 < (S_ - 2) / 2; ++p2) {
    STEP(0, 1, P0, PV1a, PV2a)
    STEP(1, 0, P1, PV1b, PV2b)
  }

  // ---- tail step s = 2047 (RB = 0): no store, no barrier
  float own;
  {
    const float4 q = ((const float4*)&mpT[0][0])[l & 3];
    const unsigned char* xb = &Xl[0][0];
    f16x8 av[8];
#pragma unroll
    for (int kk = 0; kk < 8; ++kk) av[kk] = *(const f16x8*)(xb + raddr[kk]);
    f32x4 z4 = {0.f, 0.f, 0.f, 0.f};
    f32x4 aL0 = z4, aH0 = z4, aL1 = z4, aH1 = z4;
#pragma unroll
    for (int kk = 0; kk < 4; ++kk) {
      aL0 = mfma16h(av[kk], wf[0][kk], aL0);
      aL1 = mfma16h(av[kk], wf[1][kk], aL1);
    }
#pragma unroll
    for (int kk = 4; kk < 8; ++kk) {
      aH0 = mfma16h(av[kk], wf[0][kk], aH0);
      aH1 = mfma16h(av[kk], wf[1][kk], aH1);
    }
    float v1a = 0.f, v1b = 0.f, v1c = 0.f, v1d = 0.f;
    float v2a = 0.f, v2b = 0.f, v2c = 0.f, v2d = 0.f;
#pragma unroll
    for (int kk = 0; kk < 8; ++kk) {
      const u32x4 u = __builtin_bit_cast(u32x4, av[kk]);
      const half2_t h0 = __builtin_bit_cast(half2_t, u.x);
      const half2_t h1 = __builtin_bit_cast(half2_t, u.y);
      const half2_t h2 = __builtin_bit_cast(half2_t, u.z);
      const half2_t h3 = __builtin_bit_cast(half2_t, u.w);
      v1a = fdot2f(h0, Wd1[kk][0], v1a);
      v1b = fdot2f(h1, Wd1[kk][1], v1b);
      v1c = fdot2f(h2, Wd1[kk][2], v1c);
      v1d = fdot2f(h3, Wd1[kk][3], v1d);
      v2a = fdot2f(h0, Wd2[kk][0], v2a);
      v2b = fdot2f(h1, Wd2[kk][1], v2b);
      v2c = fdot2f(h2, Wd2[kk][2], v2c);
      v2d = fdot2f(h3, Wd2[kk][3], v2d);
    }
    float zv1 = (v1a + v1b) + (v1c + v1d);
    float zv2 = (v2a + v2b) + (v2c + v2d);
    zv1 += __shfl_xor(zv1, 16); zv1 += __shfl_xor(zv1, 32);
    zv2 += __shfl_xor(zv2, 16); zv2 += __shfl_xor(zv2, 32);
    float mh = fmaxf(fmaxf(q.x, q.y), fmaxf(q.z, q.w));
    mh = dpp_max<0xB1>(mh);
    mh = dpp_max<0x4E>(mh);
    int ue = (int)(__builtin_bit_cast(unsigned, mh) >> 23) - 127;
    ue = (ue < -20) ? -20 : ue;
    ue += 8;
    k_run += ue;
    const float kln = -0.6931471805599453f * (float)ue;
    const float EcRs = __expf(P0 + kln);
    const float EcRsV1 = __expf(PV1a + kln);
    const float EcRsV2 = __expf(PV2a + kln);
    const f32x4 ac0 = aL0 + aH0, ac1 = aL1 + aH1;
    const float valm = (hi & 1) ? ac1[0] : ac0[0];
    const float xm = valm * EcRs;
    const float xv1 = zv1 * EcRsV1;
    const float xv2 = zv2 * EcRsV2;
    own = (hi < 2) ? xm : ((hi == 2) ? xv1 : xv2);
  }

  // ---- epilogue: logZ = m0 + k_run*ln2 + log(sum_j x[j]*exp(end[j]))
  float f = own * __expf(endt[jE]);
  f = dpp_add<0xB1>(f);
  f = dpp_add<0x4E>(f);
  f = dpp_add<0x141>(f);
  f = dpp_add<0x140>(f);
  f += __shfl_xor(f, 16);
  f += __shfl_xor(f, 32);
  __syncthreads();  // fsum reuse
  if (l == 0) fsum[w] = f;
  __syncthreads();
  if (tid == 0) {
    const float tot = (fsum[0] + fsum[1]) + (fsum[2] + fsum[3]);
    ws[64 + blockIdx.x] = m0 + (float)k_run * 0.6931471805599453f + __logf(tot);
  }
}

// ---------------- final: mean_b(score - logZ) ----------------
__global__ void crf_final(const float* __restrict__ ws, float* __restrict__ out) {
  const int t = threadIdx.x;  // 64
  float v = ws[t] - ws[64 + t];
#pragma unroll
  for (int off = 1; off <= 32; off <<= 1) v += __shfl_xor(v, off);
  if (t == 0) out[0] = v * (1.0f / 64.0f);
}

extern "C" void kernel_launch(void* const* d_in, const int* in_sizes, int n_in,
                              void* d_out, int out_size, void* d_ws, size_t ws_size,
                              hipStream_t stream) {
  const float* em = (const float*)d_in[0];
  const int* tags = (const int*)d_in[1];
  const int* mask = (const int*)d_in[2];
  const float* trans = (const float*)d_in[3];
  const float* startt = (const float*)d_in[4];
  const float* endt = (const float*)d_in[5];
  float* out = (float*)d_out;
  float* ws = (float*)d_ws;

  crf_score<<<B_, 256, 0, stream>>>(em, tags, mask, trans, startt, endt, ws);
  crf_forward<<<B_, 256, 0, stream>>>(em, trans, startt, endt, ws);
  crf_final<<<1, 64, 0, stream>>>(ws, out);
}